// Round 6
// baseline (561.059 us; speedup 1.0000x reference)
//
#include <hip/hip_runtime.h>

#define D 64
#define NPB_SHIFT 9                    // 512 dst nodes per bucket
#define NPB (1 << NPB_SHIFT)
#define NB 196                         // ceil(100000/512)
#define CHUNK 8192                     // edges per multisplit block (32 KB LDS stage)

// ---------- K0: f32 -> bf16(RNE) packed feature tables ----------
__device__ __forceinline__ unsigned bf16rne(float x) {
    unsigned u = __float_as_uint(x);
    return (u + 0x7fffu + ((u >> 16) & 1u)) >> 16;
}
__global__ __launch_bounds__(256) void to_bf16(
    const float* __restrict__ fu, const float* __restrict__ fi,
    unsigned* __restrict__ bu, unsigned* __restrict__ bi, int n4)
{
    const float4* src = blockIdx.y == 0 ? (const float4*)fu : (const float4*)fi;
    uint2* dst = blockIdx.y == 0 ? (uint2*)bu : (uint2*)bi;
    for (int i = blockIdx.x * 256 + threadIdx.x; i < n4; i += gridDim.x * 256) {
        const float4 v = src[i];
        uint2 r;
        r.x = bf16rne(v.x) | (bf16rne(v.y) << 16);
        r.y = bf16rne(v.z) | (bf16rne(v.w) << 16);
        dst[i] = r;
    }
}

// ---------- K1: per-(etype,bucket) histogram, LDS-aggregated ----------
__global__ __launch_bounds__(256) void bkt_hist(
    const int* __restrict__ d0, const int* __restrict__ d1, const int* __restrict__ d2,
    int* __restrict__ hist, int nE)
{
    const int et = blockIdx.y;
    const int* dst = et == 0 ? d0 : (et == 1 ? d1 : d2);
    __shared__ int h[NB];
    for (int i = threadIdx.x; i < NB; i += 256) h[i] = 0;
    __syncthreads();
    for (int e = blockIdx.x * 256 + threadIdx.x; e < nE; e += gridDim.x * 256)
        atomicAdd(&h[dst[e] >> NPB_SHIFT], 1);
    __syncthreads();
    int* gh = hist + et * NB;
    for (int i = threadIdx.x; i < NB; i += 256)
        if (h[i]) atomicAdd(&gh[i], h[i]);
}

// ---------- K2: exclusive scan of hist[et][0..NB) -> off; init gcur ----------
__global__ __launch_bounds__(256) void bkt_scan(
    const int* __restrict__ hist, int* __restrict__ off, int* __restrict__ gcur)
{
    const int et = blockIdx.x;
    const int tid = threadIdx.x;
    const int v = tid < NB ? hist[et * NB + tid] : 0;
    int inc = v;
#pragma unroll
    for (int of = 1; of < 64; of <<= 1) {
        int t = __shfl_up(inc, of);
        if ((tid & 63) >= of) inc += t;
    }
    __shared__ int ws[4];
    if ((tid & 63) == 63) ws[tid >> 6] = inc;
    __syncthreads();
    int woff = 0;
    for (int i = 0; i < (tid >> 6); ++i) woff += ws[i];
    const int excl = woff + inc - v;
    if (tid < NB) { off[et * NB + tid] = excl; gcur[et * NB + tid] = excl; }
}

// ---------- K3: LDS multisplit scatter into bucket regions ----------
__global__ __launch_bounds__(256) void bkt_multisplit(
    const int* __restrict__ s0, const int* __restrict__ d0,
    const int* __restrict__ s1, const int* __restrict__ d1,
    const int* __restrict__ s2, const int* __restrict__ d2,
    int* __restrict__ gcur, int* __restrict__ bkt, int nE, int E)
{
    const int et = blockIdx.y;
    const int* src = et == 0 ? s0 : (et == 1 ? s1 : s2);
    const int* dst = et == 0 ? d0 : (et == 1 ? d1 : d2);
    int* gc = gcur + et * NB;
    int* bk = bkt + (size_t)et * E;

    __shared__ int h[NB];
    __shared__ int st[NB];
    __shared__ int cu[NB];
    __shared__ int gb[NB];
    __shared__ int ws[4];
    __shared__ int stage[CHUNK];

    const int tid = threadIdx.x;
    const int e0 = blockIdx.x * CHUNK;
    const int e1 = min(e0 + CHUNK, nE);

    for (int i = tid; i < NB; i += 256) h[i] = 0;
    __syncthreads();
    for (int e = e0 + tid; e < e1; e += 256)
        atomicAdd(&h[dst[e] >> NPB_SHIFT], 1);
    __syncthreads();

    const int v = tid < NB ? h[tid] : 0;
    int inc = v;
#pragma unroll
    for (int of = 1; of < 64; of <<= 1) {
        int t = __shfl_up(inc, of);
        if ((tid & 63) >= of) inc += t;
    }
    if ((tid & 63) == 63) ws[tid >> 6] = inc;
    __syncthreads();
    int woff = 0;
    for (int i = 0; i < (tid >> 6); ++i) woff += ws[i];
    const int excl = woff + inc - v;
    if (tid < NB) {
        st[tid] = excl;
        cu[tid] = excl;
        if (v > 0) gb[tid] = atomicAdd(&gc[tid], v);
    }
    __syncthreads();

    for (int e = e0 + tid; e < e1; e += 256) {
        const int dd = dst[e];
        const int b = dd >> NPB_SHIFT;
        const int pos = atomicAdd(&cu[b], 1);
        stage[pos] = src[e] | ((dd & (NPB - 1)) << 17);
    }
    __syncthreads();

    const int wv = tid >> 6, ln = tid & 63;
    for (int b = wv; b < NB; b += 4) {
        const int cb = h[b];
        if (cb == 0) continue;
        const int base = st[b], g = gb[b];
        for (int i = ln; i < cb; i += 64)
            bk[g + i] = stage[base + i];
    }
}

// ---------- K4: per-bucket CSR finalize ----------
__global__ __launch_bounds__(256) void bkt_csr(
    const int* __restrict__ off, const int* __restrict__ bkt_all,
    int* __restrict__ rp_all, int* __restrict__ cnt_all, int* __restrict__ lst_all,
    int N, int E)
{
    const int et = blockIdx.y;
    const int b = blockIdx.x;
    const int* o = off + et * NB;
    const int* bk = bkt_all + (size_t)et * E;
    int* lst = lst_all + (size_t)et * E;
    int* rp  = rp_all  + (size_t)et * N;
    int* cnt = cnt_all + (size_t)et * N;
    const int A  = o[b];
    const int Bb = (b + 1 < NB) ? o[b + 1] : E;

    __shared__ int h[NPB];
    __shared__ int cu[NPB];
    __shared__ int ws2[4];
    for (int i = threadIdx.x; i < NPB; i += 256) h[i] = 0;
    __syncthreads();
    for (int i = A + threadIdx.x; i < Bb; i += 256)
        atomicAdd(&h[((unsigned)bk[i]) >> 17], 1);
    __syncthreads();

    const int tid = threadIdx.x;
    const int v0 = h[2 * tid], v1 = h[2 * tid + 1];
    const int tsum = v0 + v1;
    int inc = tsum;
#pragma unroll
    for (int of = 1; of < 64; of <<= 1) {
        int t = __shfl_up(inc, of);
        if ((tid & 63) >= of) inc += t;
    }
    if ((tid & 63) == 63) ws2[tid >> 6] = inc;
    __syncthreads();
    int woff = 0;
    for (int i = 0; i < (tid >> 6); ++i) woff += ws2[i];
    const int excl = woff + inc - tsum;
    cu[2 * tid] = excl;
    cu[2 * tid + 1] = excl + v0;
    const int n0 = b << NPB_SHIFT;
    if (n0 + 2 * tid < N)     { cnt[n0 + 2 * tid]     = v0; rp[n0 + 2 * tid]     = A + excl; }
    if (n0 + 2 * tid + 1 < N) { cnt[n0 + 2 * tid + 1] = v1; rp[n0 + 2 * tid + 1] = A + excl + v0; }
    __syncthreads();

    for (int i = A + threadIdx.x; i < Bb; i += 256) {
        const int w = bk[i];
        const int dl = ((unsigned)w) >> 17;
        const int pos = atomicAdd(&cu[dl], 1);
        lst[A + pos] = w & 0x1FFFF;
    }
}

// ---------- K5: gather(bf16, 2 edges/wave-load) + mean + fused projection ----------
template <bool RMW>
__global__ __launch_bounds__(256) void gather_proj_bf16(
    const unsigned* __restrict__ feat,   // packed rows: 32 uints (= 64 bf16) per node
    const int* __restrict__ rp, const int* __restrict__ cnt, const int* __restrict__ lst,
    const float* __restrict__ W, const float* __restrict__ bias,
    float* __restrict__ out, int N)
{
    __shared__ float WT[64][65];   // [k][o]
    __shared__ float bs[64];
    for (int i = threadIdx.x; i < 4096; i += 256)
        WT[i & 63][i >> 6] = W[i];
    if (threadIdx.x < 64) bs[threadIdx.x] = bias[threadIdx.x];
    __syncthreads();

    const int tid = threadIdx.x;
    const int lane = tid & 63;
    const int k = lane & 31;      // dim-pair index (dims 2k, 2k+1)
    const int p = lane >> 5;      // edge parity (0: even edge, 1: odd edge)
    const int n = blockIdx.x * 4 + (tid >> 6);
    if (n >= N) return;

    const int deg = cnt[n];
    const int start = rp[n];
    float sx = 0.0f, sy = 0.0f;
    int e = 0;
    // full blocks: 16 edges, 8 wave-loads in flight, no masking
    for (; e + 16 <= deg; e += 16) {
        int id[8];
#pragma unroll
        for (int j = 0; j < 8; ++j)
            id[j] = lst[start + e + 2 * j + p];
        unsigned w[8];
#pragma unroll
        for (int j = 0; j < 8; ++j)
            w[j] = feat[id[j] * 32 + k];
#pragma unroll
        for (int j = 0; j < 8; ++j) {
            sx += __uint_as_float(w[j] << 16);
            sy += __uint_as_float(w[j] & 0xffff0000u);
        }
    }
    // tail (<16 edges), 2 per step, masked
    for (; e < deg; e += 2) {
        const int ee = e + p;
        const bool ok = ee < deg;
        const int id = ok ? lst[start + ee] : 0;
        const unsigned w = feat[id * 32 + k];
        if (ok) {
            sx += __uint_as_float(w << 16);
            sy += __uint_as_float(w & 0xffff0000u);
        }
    }
    // combine the two edge-parity halves (lanes k and k+32 hold same dim pair)
    sx += __shfl_xor(sx, 32);
    sy += __shfl_xor(sy, 32);
    const float inv = deg > 0 ? 1.0f / (float)deg : 0.0f;
    const float mx = sx * inv;   // mean of dim 2k   (valid in all lanes' k-slot)
    const float my = sy * inv;   // mean of dim 2k+1

    float a0 = deg > 0 ? bs[lane] : 0.0f;
    float a1 = 0.0f, a2 = 0.0f, a3 = 0.0f;
#pragma unroll
    for (int k2 = 0; k2 < 32; k2 += 2) {
        a0 = fmaf(__shfl(mx, k2),     WT[2 * k2][lane],     a0);
        a1 = fmaf(__shfl(my, k2),     WT[2 * k2 + 1][lane], a1);
        a2 = fmaf(__shfl(mx, k2 + 1), WT[2 * k2 + 2][lane], a2);
        a3 = fmaf(__shfl(my, k2 + 1), WT[2 * k2 + 3][lane], a3);
    }
    float r = (a0 + a1) + (a2 + a3);
    if (RMW) r += out[n * D + lane];
    out[n * D + lane] = r;
}

extern "C" void kernel_launch(void* const* d_in, const int* in_sizes, int n_in,
                              void* d_out, int out_size, void* d_ws, size_t ws_size,
                              hipStream_t stream)
{
    const float* feat_user = (const float*)d_in[0];
    const float* feat_item = (const float*)d_in[1];
    const float* W_f  = (const float*)d_in[2];
    const float* b_f  = (const float*)d_in[3];
    const float* W_r  = (const float*)d_in[4];
    const float* b_r  = (const float*)d_in[5];
    const float* W_rb = (const float*)d_in[6];
    const float* b_rb = (const float*)d_in[7];
    const int* src_f  = (const int*)d_in[8];
    const int* dst_f  = (const int*)d_in[9];
    const int* src_r  = (const int*)d_in[10];
    const int* dst_r  = (const int*)d_in[11];
    const int* src_rb = (const int*)d_in[12];
    const int* dst_rb = (const int*)d_in[13];
    float* out = (float*)d_out;

    const int NU = in_sizes[0] / D;   // 100000
    const int NI = in_sizes[1] / D;   // 100000 (== NU)
    const int E  = in_sizes[8];       // 1.6M per etype
    const int N  = NU;

    // Workspace (ints then packed bf16 tables); ~66 MB, R1 proved >= 78 MB available
    int* hist = (int*)d_ws;           // [3][NB]
    int* off  = hist + 3 * NB;
    int* gcur = off  + 3 * NB;
    int* rp   = gcur + 3 * NB;        // [3][N]
    int* cnt  = rp   + 3 * (size_t)N;
    int* bkt  = cnt  + 3 * (size_t)N; // [3][E]
    int* lst  = bkt  + 3 * (size_t)E; // [3][E]
    unsigned* fbu = (unsigned*)(lst + 3 * (size_t)E);  // [N*32] packed bf16 user feats
    unsigned* fbi = fbu + (size_t)N * 32;              // [N*32] packed bf16 item feats

    hipMemsetAsync(hist, 0, (size_t)3 * NB * sizeof(int), stream);

    const dim3 blk(256);
    const int n4 = N * D / 4;
    to_bf16<<<dim3(2048, 2), blk, 0, stream>>>(feat_user, feat_item, fbu, fbi, n4);

    // etype order: 0=follows(dst user), 1=ratedby(dst user), 2=rates(dst item)
    bkt_hist<<<dim3(256, 3), blk, 0, stream>>>(dst_f, dst_rb, dst_r, hist, E);
    bkt_scan<<<3, blk, 0, stream>>>(hist, off, gcur);
    const int nms = (E + CHUNK - 1) / CHUNK;
    bkt_multisplit<<<dim3(nms, 3), blk, 0, stream>>>(
        src_f, dst_f, src_rb, dst_rb, src_r, dst_r, gcur, bkt, E, E);
    bkt_csr<<<dim3(NB, 3), blk, 0, stream>>>(off, bkt, rp, cnt, lst, N, E);

    int* rp_f  = rp;            int* cnt_f  = cnt;            int* lst_f  = lst;
    int* rp_rb = rp + N;        int* cnt_rb = cnt + N;        int* lst_rb = lst + E;
    int* rp_r  = rp + 2 * N;    int* cnt_r  = cnt + 2 * N;    int* lst_r  = lst + 2 * (size_t)E;

    const int gblk = (N + 3) / 4;
    // users: follows (store), then ratedby (RMW) -> cross-etype sum
    gather_proj_bf16<false><<<gblk, blk, 0, stream>>>(
        fbu, rp_f, cnt_f, lst_f, W_f, b_f, out, NU);
    gather_proj_bf16<true><<<gblk, blk, 0, stream>>>(
        fbi, rp_rb, cnt_rb, lst_rb, W_rb, b_rb, out, NU);
    // items: rates (store)
    gather_proj_bf16<false><<<gblk, blk, 0, stream>>>(
        fbu, rp_r, cnt_r, lst_r, W_r, b_r, out + (size_t)NU * D, NI);
}

// Round 7
// 498.826 us; speedup vs baseline: 1.1248x; 1.1248x over previous
//
#include <hip/hip_runtime.h>

#define D 64
#define NPB_SHIFT 9                    // 512 dst nodes per bucket
#define NPB (1 << NPB_SHIFT)
#define NB 196                         // ceil(100000/512)
#define CHUNK 8192                     // edges per multisplit block (32 KB LDS stage)

// ---------- K0: f32 -> bf16(RNE) packed feature tables ----------
__device__ __forceinline__ unsigned bf16rne(float x) {
    unsigned u = __float_as_uint(x);
    return (u + 0x7fffu + ((u >> 16) & 1u)) >> 16;
}
__global__ __launch_bounds__(256) void to_bf16(
    const float* __restrict__ fu, const float* __restrict__ fi,
    unsigned* __restrict__ bu, unsigned* __restrict__ bi, int n4)
{
    const float4* src = blockIdx.y == 0 ? (const float4*)fu : (const float4*)fi;
    uint2* dst = blockIdx.y == 0 ? (uint2*)bu : (uint2*)bi;
    for (int i = blockIdx.x * 256 + threadIdx.x; i < n4; i += gridDim.x * 256) {
        const float4 v = src[i];
        uint2 r;
        r.x = bf16rne(v.x) | (bf16rne(v.y) << 16);
        r.y = bf16rne(v.z) | (bf16rne(v.w) << 16);
        dst[i] = r;
    }
}

// ---------- K1: per-(etype,bucket) histogram, LDS-aggregated ----------
__global__ __launch_bounds__(256) void bkt_hist(
    const int* __restrict__ d0, const int* __restrict__ d1, const int* __restrict__ d2,
    int* __restrict__ hist, int nE)
{
    const int et = blockIdx.y;
    const int* dst = et == 0 ? d0 : (et == 1 ? d1 : d2);
    __shared__ int h[NB];
    for (int i = threadIdx.x; i < NB; i += 256) h[i] = 0;
    __syncthreads();
    for (int e = blockIdx.x * 256 + threadIdx.x; e < nE; e += gridDim.x * 256)
        atomicAdd(&h[dst[e] >> NPB_SHIFT], 1);
    __syncthreads();
    int* gh = hist + et * NB;
    for (int i = threadIdx.x; i < NB; i += 256)
        if (h[i]) atomicAdd(&gh[i], h[i]);
}

// ---------- K2: exclusive scan of hist[et][0..NB) -> off; init gcur ----------
__global__ __launch_bounds__(256) void bkt_scan(
    const int* __restrict__ hist, int* __restrict__ off, int* __restrict__ gcur)
{
    const int et = blockIdx.x;
    const int tid = threadIdx.x;
    const int v = tid < NB ? hist[et * NB + tid] : 0;
    int inc = v;
#pragma unroll
    for (int of = 1; of < 64; of <<= 1) {
        int t = __shfl_up(inc, of);
        if ((tid & 63) >= of) inc += t;
    }
    __shared__ int ws[4];
    if ((tid & 63) == 63) ws[tid >> 6] = inc;
    __syncthreads();
    int woff = 0;
    for (int i = 0; i < (tid >> 6); ++i) woff += ws[i];
    const int excl = woff + inc - v;
    if (tid < NB) { off[et * NB + tid] = excl; gcur[et * NB + tid] = excl; }
}

// ---------- K3: LDS multisplit scatter into bucket regions ----------
__global__ __launch_bounds__(256) void bkt_multisplit(
    const int* __restrict__ s0, const int* __restrict__ d0,
    const int* __restrict__ s1, const int* __restrict__ d1,
    const int* __restrict__ s2, const int* __restrict__ d2,
    int* __restrict__ gcur, int* __restrict__ bkt, int nE, int E)
{
    const int et = blockIdx.y;
    const int* src = et == 0 ? s0 : (et == 1 ? s1 : s2);
    const int* dst = et == 0 ? d0 : (et == 1 ? d1 : d2);
    int* gc = gcur + et * NB;
    int* bk = bkt + (size_t)et * E;

    __shared__ int h[NB];
    __shared__ int st[NB];
    __shared__ int cu[NB];
    __shared__ int gb[NB];
    __shared__ int ws[4];
    __shared__ int stage[CHUNK];

    const int tid = threadIdx.x;
    const int e0 = blockIdx.x * CHUNK;
    const int e1 = min(e0 + CHUNK, nE);

    for (int i = tid; i < NB; i += 256) h[i] = 0;
    __syncthreads();
    for (int e = e0 + tid; e < e1; e += 256)
        atomicAdd(&h[dst[e] >> NPB_SHIFT], 1);
    __syncthreads();

    const int v = tid < NB ? h[tid] : 0;
    int inc = v;
#pragma unroll
    for (int of = 1; of < 64; of <<= 1) {
        int t = __shfl_up(inc, of);
        if ((tid & 63) >= of) inc += t;
    }
    if ((tid & 63) == 63) ws[tid >> 6] = inc;
    __syncthreads();
    int woff = 0;
    for (int i = 0; i < (tid >> 6); ++i) woff += ws[i];
    const int excl = woff + inc - v;
    if (tid < NB) {
        st[tid] = excl;
        cu[tid] = excl;
        if (v > 0) gb[tid] = atomicAdd(&gc[tid], v);
    }
    __syncthreads();

    for (int e = e0 + tid; e < e1; e += 256) {
        const int dd = dst[e];
        const int b = dd >> NPB_SHIFT;
        const int pos = atomicAdd(&cu[b], 1);
        stage[pos] = src[e] | ((dd & (NPB - 1)) << 17);
    }
    __syncthreads();

    const int wv = tid >> 6, ln = tid & 63;
    for (int b = wv; b < NB; b += 4) {
        const int cb = h[b];
        if (cb == 0) continue;
        const int base = st[b], g = gb[b];
        for (int i = ln; i < cb; i += 64)
            bk[g + i] = stage[base + i];
    }
}

// ---------- K4: per-bucket CSR finalize ----------
__global__ __launch_bounds__(256) void bkt_csr(
    const int* __restrict__ off, const int* __restrict__ bkt_all,
    int* __restrict__ rp_all, int* __restrict__ cnt_all, int* __restrict__ lst_all,
    int N, int E)
{
    const int et = blockIdx.y;
    const int b = blockIdx.x;
    const int* o = off + et * NB;
    const int* bk = bkt_all + (size_t)et * E;
    int* lst = lst_all + (size_t)et * E;
    int* rp  = rp_all  + (size_t)et * N;
    int* cnt = cnt_all + (size_t)et * N;
    const int A  = o[b];
    const int Bb = (b + 1 < NB) ? o[b + 1] : E;

    __shared__ int h[NPB];
    __shared__ int cu[NPB];
    __shared__ int ws2[4];
    for (int i = threadIdx.x; i < NPB; i += 256) h[i] = 0;
    __syncthreads();
    for (int i = A + threadIdx.x; i < Bb; i += 256)
        atomicAdd(&h[((unsigned)bk[i]) >> 17], 1);
    __syncthreads();

    const int tid = threadIdx.x;
    const int v0 = h[2 * tid], v1 = h[2 * tid + 1];
    const int tsum = v0 + v1;
    int inc = tsum;
#pragma unroll
    for (int of = 1; of < 64; of <<= 1) {
        int t = __shfl_up(inc, of);
        if ((tid & 63) >= of) inc += t;
    }
    if ((tid & 63) == 63) ws2[tid >> 6] = inc;
    __syncthreads();
    int woff = 0;
    for (int i = 0; i < (tid >> 6); ++i) woff += ws2[i];
    const int excl = woff + inc - tsum;
    cu[2 * tid] = excl;
    cu[2 * tid + 1] = excl + v0;
    const int n0 = b << NPB_SHIFT;
    if (n0 + 2 * tid < N)     { cnt[n0 + 2 * tid]     = v0; rp[n0 + 2 * tid]     = A + excl; }
    if (n0 + 2 * tid + 1 < N) { cnt[n0 + 2 * tid + 1] = v1; rp[n0 + 2 * tid + 1] = A + excl + v0; }
    __syncthreads();

    for (int i = A + threadIdx.x; i < Bb; i += 256) {
        const int w = bk[i];
        const int dl = ((unsigned)w) >> 17;
        const int pos = atomicAdd(&cu[dl], 1);
        lst[A + pos] = w & 0x1FFFF;
    }
}

// ---------- K5: gather(bf16, 2 edges/wave-load) + mean + fused projection ----------
// Uniform masked 16-edge batches (clamped idx, fmaf mask) + cross-batch idx prefetch:
// zero serial load generations per node beyond ceil(deg/16).
template <bool RMW>
__global__ __launch_bounds__(256) void gather_proj_bf16(
    const unsigned* __restrict__ feat,   // packed rows: 32 uints (= 64 bf16) per node
    const int* __restrict__ rp, const int* __restrict__ cnt, const int* __restrict__ lst,
    const float* __restrict__ W, const float* __restrict__ bias,
    float* __restrict__ out, int N)
{
    __shared__ float WT[64][65];   // [k][o]
    __shared__ float bs[64];
    for (int i = threadIdx.x; i < 4096; i += 256)
        WT[i & 63][i >> 6] = W[i];
    if (threadIdx.x < 64) bs[threadIdx.x] = bias[threadIdx.x];
    __syncthreads();

    const int tid = threadIdx.x;
    const int lane = tid & 63;
    const int k = lane & 31;      // dim-pair index (dims 2k, 2k+1)
    const int p = lane >> 5;      // edge parity (0: even edge, 1: odd edge)
    const int n = blockIdx.x * 4 + (tid >> 6);
    if (n >= N) return;

    const int deg = cnt[n];
    const int start = rp[n];
    float sx = 0.0f, sy = 0.0f;

    if (deg > 0) {
        int id[8];
        float mk[8];
#pragma unroll
        for (int j = 0; j < 8; ++j) {                     // batch e=0 indices
            const int ee = 2 * j + p;
            id[j] = lst[start + (ee < deg ? ee : deg - 1)];
            mk[j] = ee < deg ? 1.0f : 0.0f;
        }
        for (int e = 0; e < deg; e += 16) {
            unsigned w[8];
#pragma unroll
            for (int j = 0; j < 8; ++j)                   // 8 feature rows in flight
                w[j] = feat[id[j] * 32 + k];
            const bool more = (e + 16) < deg;             // wave-uniform
            int id2[8];
            float mk2[8];
            if (more) {                                   // prefetch next batch's idx
#pragma unroll
                for (int j = 0; j < 8; ++j) {
                    const int ee = e + 16 + 2 * j + p;
                    id2[j] = lst[start + (ee < deg ? ee : deg - 1)];
                    mk2[j] = ee < deg ? 1.0f : 0.0f;
                }
            }
#pragma unroll
            for (int j = 0; j < 8; ++j) {
                sx = fmaf(mk[j], __uint_as_float(w[j] << 16), sx);
                sy = fmaf(mk[j], __uint_as_float(w[j] & 0xffff0000u), sy);
            }
            if (more) {
#pragma unroll
                for (int j = 0; j < 8; ++j) { id[j] = id2[j]; mk[j] = mk2[j]; }
            }
        }
    }
    // combine the two edge-parity halves (lanes k and k+32 hold same dim pair)
    sx += __shfl_xor(sx, 32);
    sy += __shfl_xor(sy, 32);
    const float inv = deg > 0 ? 1.0f / (float)deg : 0.0f;
    const float mx = sx * inv;   // mean of dim 2k
    const float my = sy * inv;   // mean of dim 2k+1

    float a0 = deg > 0 ? bs[lane] : 0.0f;
    float a1 = 0.0f, a2 = 0.0f, a3 = 0.0f;
#pragma unroll
    for (int k2 = 0; k2 < 32; k2 += 2) {
        a0 = fmaf(__shfl(mx, k2),     WT[2 * k2][lane],     a0);
        a1 = fmaf(__shfl(my, k2),     WT[2 * k2 + 1][lane], a1);
        a2 = fmaf(__shfl(mx, k2 + 1), WT[2 * k2 + 2][lane], a2);
        a3 = fmaf(__shfl(my, k2 + 1), WT[2 * k2 + 3][lane], a3);
    }
    float r = (a0 + a1) + (a2 + a3);
    if (RMW) r += out[n * D + lane];
    out[n * D + lane] = r;
}

extern "C" void kernel_launch(void* const* d_in, const int* in_sizes, int n_in,
                              void* d_out, int out_size, void* d_ws, size_t ws_size,
                              hipStream_t stream)
{
    const float* feat_user = (const float*)d_in[0];
    const float* feat_item = (const float*)d_in[1];
    const float* W_f  = (const float*)d_in[2];
    const float* b_f  = (const float*)d_in[3];
    const float* W_r  = (const float*)d_in[4];
    const float* b_r  = (const float*)d_in[5];
    const float* W_rb = (const float*)d_in[6];
    const float* b_rb = (const float*)d_in[7];
    const int* src_f  = (const int*)d_in[8];
    const int* dst_f  = (const int*)d_in[9];
    const int* src_r  = (const int*)d_in[10];
    const int* dst_r  = (const int*)d_in[11];
    const int* src_rb = (const int*)d_in[12];
    const int* dst_rb = (const int*)d_in[13];
    float* out = (float*)d_out;

    const int NU = in_sizes[0] / D;   // 100000
    const int NI = in_sizes[1] / D;   // 100000 (== NU)
    const int E  = in_sizes[8];       // 1.6M per etype
    const int N  = NU;

    // Workspace (ints then packed bf16 tables); ~66 MB
    int* hist = (int*)d_ws;           // [3][NB]
    int* off  = hist + 3 * NB;
    int* gcur = off  + 3 * NB;
    int* rp   = gcur + 3 * NB;        // [3][N]
    int* cnt  = rp   + 3 * (size_t)N;
    int* bkt  = cnt  + 3 * (size_t)N; // [3][E]
    int* lst  = bkt  + 3 * (size_t)E; // [3][E]
    unsigned* fbu = (unsigned*)(lst + 3 * (size_t)E);  // [N*32] packed bf16 user feats
    unsigned* fbi = fbu + (size_t)N * 32;              // [N*32] packed bf16 item feats

    hipMemsetAsync(hist, 0, (size_t)3 * NB * sizeof(int), stream);

    const dim3 blk(256);
    const int n4 = N * D / 4;
    to_bf16<<<dim3(2048, 2), blk, 0, stream>>>(feat_user, feat_item, fbu, fbi, n4);

    // etype order: 0=follows(dst user), 1=ratedby(dst user), 2=rates(dst item)
    bkt_hist<<<dim3(256, 3), blk, 0, stream>>>(dst_f, dst_rb, dst_r, hist, E);
    bkt_scan<<<3, blk, 0, stream>>>(hist, off, gcur);
    const int nms = (E + CHUNK - 1) / CHUNK;
    bkt_multisplit<<<dim3(nms, 3), blk, 0, stream>>>(
        src_f, dst_f, src_rb, dst_rb, src_r, dst_r, gcur, bkt, E, E);
    bkt_csr<<<dim3(NB, 3), blk, 0, stream>>>(off, bkt, rp, cnt, lst, N, E);

    int* rp_f  = rp;            int* cnt_f  = cnt;            int* lst_f  = lst;
    int* rp_rb = rp + N;        int* cnt_rb = cnt + N;        int* lst_rb = lst + E;
    int* rp_r  = rp + 2 * N;    int* cnt_r  = cnt + 2 * N;    int* lst_r  = lst + 2 * (size_t)E;

    const int gblk = (N + 3) / 4;
    // users: follows (store), then ratedby (RMW) -> cross-etype sum
    gather_proj_bf16<false><<<gblk, blk, 0, stream>>>(
        fbu, rp_f, cnt_f, lst_f, W_f, b_f, out, NU);
    gather_proj_bf16<true><<<gblk, blk, 0, stream>>>(
        fbi, rp_rb, cnt_rb, lst_rb, W_rb, b_rb, out, NU);
    // items: rates (store)
    gather_proj_bf16<false><<<gblk, blk, 0, stream>>>(
        fbu, rp_r, cnt_r, lst_r, W_r, b_r, out + (size_t)NU * D, NI);
}